// Round 8
// baseline (610.622 us; speedup 1.0000x reference)
//
#include <hip/hip_runtime.h>
#include <hip/hip_fp16.h>

#define NU 100000
#define NI 50000
#define D  64
#define CAPU 64   // rate slots per user  (2 classes, front/back shared 64)
#define CAPI 96   // rate slots per item  (4 classes: two 48-slot halves, front/back)
#define CAPT 32   // trust slots per dst  (2 classes, front/back shared 32)
#define BS 256

// counting-sort geometry
#define NB1 256
#define KPB1 391      // ceil(NU/NB1)
#define CAPB1 9216
#define NB2 256
#define KPB2 196      // ceil(NI/NB2)
#define CAPB2 9216
#define NB3 128
#define KPB3 782      // ceil(NU/NB3)
#define CAPB3 4864
#define NB4 128
#define CAPB4 4864
#define GR 224        // rate bin blocks
#define GT 32         // trust bin blocks

typedef unsigned long long u64;

// ---------------- pass A: LDS-histogram binning, 4 sorts at once ----------------
__global__ void __launch_bounds__(1024) k_binAll(
    const int* __restrict__ ru, const int* __restrict__ ri,
    const int* __restrict__ ts, const int* __restrict__ td,
    int* __restrict__ bc1, int* __restrict__ bc2,
    int* __restrict__ bc3, int* __restrict__ bc4,
    u64* __restrict__ bins1, u64* __restrict__ bins2,
    u64* __restrict__ bins3, u64* __restrict__ bins4,
    int E_rate, int E_trust)
{
    __shared__ int cnt[512];
    __shared__ int base[512];
    int b = blockIdx.x, tid = threadIdx.x;
    if (b < GR) {
        if (tid < 512) cnt[tid] = 0;
        __syncthreads();
        for (int c0 = b * 1024; c0 < E_rate; c0 += GR * 1024) {
            int e = c0 + tid;
            if (e < E_rate) {
                int u = ru[e], it = ri[e];
                atomicAdd(&cnt[u / KPB1], 1);
                atomicAdd(&cnt[256 + it / KPB2], 1);
            }
        }
        __syncthreads();
        if (tid < 256)      base[tid] = atomicAdd(&bc1[tid], cnt[tid]);
        else if (tid < 512) base[tid] = atomicAdd(&bc2[tid - 256], cnt[tid]);
        __syncthreads();
        if (tid < 512) cnt[tid] = 0;
        __syncthreads();
        for (int c0 = b * 1024; c0 < E_rate; c0 += GR * 1024) {
            int e = c0 + tid;
            if (e < E_rate) {
                int u = ru[e], it = ri[e];
                int b1 = u / KPB1, b2 = it / KPB2;
                int r1 = atomicAdd(&cnt[b1], 1);
                int o1 = base[b1] + r1;
                if (o1 < CAPB1) bins1[(size_t)b1 * CAPB1 + o1] = ((u64)u << 32) | (unsigned)it;
                int r2 = atomicAdd(&cnt[256 + b2], 1);
                int o2 = base[256 + b2] + r2;
                if (o2 < CAPB2) bins2[(size_t)b2 * CAPB2 + o2] = ((u64)it << 32) | (unsigned)u;
            }
        }
    } else {
        int bb = b - GR;
        if (tid < 256) cnt[tid] = 0;
        __syncthreads();
        for (int c0 = bb * 1024; c0 < E_trust; c0 += GT * 1024) {
            int e = c0 + tid;
            if (e < E_trust) {
                int s = ts[e], dd = td[e];
                atomicAdd(&cnt[dd / KPB3], 1);
                atomicAdd(&cnt[128 + s / KPB3], 1);
            }
        }
        __syncthreads();
        if (tid < 128)      base[tid] = atomicAdd(&bc3[tid], cnt[tid]);
        else if (tid < 256) base[tid] = atomicAdd(&bc4[tid - 128], cnt[tid]);
        __syncthreads();
        if (tid < 256) cnt[tid] = 0;
        __syncthreads();
        for (int c0 = bb * 1024; c0 < E_trust; c0 += GT * 1024) {
            int e = c0 + tid;
            if (e < E_trust) {
                int s = ts[e], dd = td[e];
                int b3 = dd / KPB3, b4 = s / KPB3;
                int r3 = atomicAdd(&cnt[b3], 1);
                int o3 = base[b3] + r3;
                if (o3 < CAPB3) bins3[(size_t)b3 * CAPB3 + o3] = ((u64)dd << 32) | (unsigned)s;
                int r4 = atomicAdd(&cnt[128 + b4], 1);
                int o4 = base[128 + b4] + r4;
                if (o4 < CAPB4) bins4[(size_t)b4 * CAPB4 + o4] = ((u64)s << 32);
            }
        }
    }
}

// ---------------- pass B: one block per bucket, LDS cursors, class-ordered lists ----------------
// Neighbor lists are laid out by source-range class so gathers sweep the source
// table slice-by-slice (per-XCD L2 residency). Per-class counts packed into deg.
__global__ void __launch_bounds__(512) k_buildAll(
    const u64* __restrict__ bins1, const u64* __restrict__ bins2,
    const u64* __restrict__ bins3, const u64* __restrict__ bins4,
    const int* __restrict__ bc1, const int* __restrict__ bc2,
    const int* __restrict__ bc3, const int* __restrict__ bc4,
    int* __restrict__ colU, int* __restrict__ colI, int* __restrict__ colT,
    int* __restrict__ degU, int* __restrict__ degI,
    int* __restrict__ degT, int* __restrict__ degS)
{
    __shared__ int cnt[1568];
    int b = blockIdx.x, tid = threadIdx.x;
    if (b < NB1) {
        // colU: key=user, val=item; 2 classes split at NI/2; front/back in 64 slots
        const u64* bins = bins1 + (size_t)b * CAPB1;
        int n = bc1[b]; if (n > CAPB1) n = CAPB1;
        int k0 = b * KPB1;
        for (int t = tid; t < 2 * KPB1; t += 512) cnt[t] = 0;
        __syncthreads();
        for (int i = tid; i < n; i += 512) {
            u64 e = bins[i];
            int k = (int)(e >> 32) - k0;
            int v = (int)(e & 0xffffffffu);
            int cls = v >= (NI / 2);
            int c = atomicAdd(&cnt[k + cls * KPB1], 1);
            if (c < CAPU) {
                int slot = cls ? (CAPU - 1 - c) : c;
                colU[(size_t)(k0 + k) * CAPU + slot] = v;
            }
        }
        __syncthreads();
        for (int t = tid; t < KPB1; t += 512) {
            int k = k0 + t;
            if (k < NU) {
                int c0 = cnt[t];          if (c0 > CAPU) c0 = CAPU;
                int c1 = cnt[t + KPB1];   if (c1 > CAPU) c1 = CAPU;
                degU[k] = c0 | (c1 << 16);
            }
        }
    } else if (b < NB1 + NB2) {
        // colI: key=item, val=user; 4 classes (user/25000); two 48-slot halves front/back
        int q = b - NB1;
        const u64* bins = bins2 + (size_t)q * CAPB2;
        int n = bc2[q]; if (n > CAPB2) n = CAPB2;
        int k0 = q * KPB2;
        for (int t = tid; t < 4 * KPB2; t += 512) cnt[t] = 0;
        __syncthreads();
        for (int i = tid; i < n; i += 512) {
            u64 e = bins[i];
            int k = (int)(e >> 32) - k0;
            int v = (int)(e & 0xffffffffu);
            int cls = v / (NU / 4);
            int c = atomicAdd(&cnt[k + cls * KPB2], 1);
            if (c < 48) {
                int slot = (cls == 0) ? c : (cls == 1) ? (47 - c)
                         : (cls == 2) ? (48 + c) : (95 - c);
                colI[(size_t)(k0 + k) * CAPI + slot] = v;
            }
        }
        __syncthreads();
        for (int t = tid; t < KPB2; t += 512) {
            int k = k0 + t;
            if (k < NI) {
                int c0 = cnt[t];            if (c0 > 48) c0 = 48;
                int c1 = cnt[t + KPB2];     if (c1 > 48) c1 = 48;
                int c2 = cnt[t + 2 * KPB2]; if (c2 > 48) c2 = 48;
                int c3 = cnt[t + 3 * KPB2]; if (c3 > 48) c3 = 48;
                degI[k] = c0 | (c1 << 8) | (c2 << 16) | (c3 << 24);
            }
        }
    } else if (b < NB1 + NB2 + NB3) {
        // colT: key=dst, val=src; 2 classes split at NU/2; front/back in 32 slots
        int q = b - NB1 - NB2;
        const u64* bins = bins3 + (size_t)q * CAPB3;
        int n = bc3[q]; if (n > CAPB3) n = CAPB3;
        int k0 = q * KPB3;
        for (int t = tid; t < 2 * KPB3; t += 512) cnt[t] = 0;
        __syncthreads();
        for (int i = tid; i < n; i += 512) {
            u64 e = bins[i];
            int k = (int)(e >> 32) - k0;
            int v = (int)(e & 0xffffffffu);
            int cls = v >= (NU / 2);
            int c = atomicAdd(&cnt[k + cls * KPB3], 1);
            if (c < CAPT) {
                int slot = cls ? (CAPT - 1 - c) : c;
                colT[(size_t)(k0 + k) * CAPT + slot] = v;
            }
        }
        __syncthreads();
        for (int t = tid; t < KPB3; t += 512) {
            int k = k0 + t;
            if (k < NU) {
                int c0 = cnt[t];          if (c0 > CAPT) c0 = CAPT;
                int c1 = cnt[t + KPB3];   if (c1 > CAPT) c1 = CAPT;
                degT[k] = c0 | (c1 << 16);
            }
        }
    } else {
        // degS: plain per-key count
        int q = b - NB1 - NB2 - NB3;
        const u64* bins = bins4 + (size_t)q * CAPB4;
        int n = bc4[q]; if (n > CAPB4) n = CAPB4;
        int k0 = q * KPB3;
        for (int t = tid; t < KPB3; t += 512) cnt[t] = 0;
        __syncthreads();
        for (int i = tid; i < n; i += 512) {
            int k = (int)(bins[i] >> 32);
            atomicAdd(&cnt[k - k0], 1);
        }
        __syncthreads();
        for (int t = tid; t < KPB3; t += 512) {
            int k = k0 + t;
            if (k < NU) degS[k] = cnt[t];
        }
    }
}

// rs = rsqrt(max(deg,1)); deg words are class-packed
__global__ void k_degrs(const int* __restrict__ degU, const int* __restrict__ degI,
                        const int* __restrict__ degT, const int* __restrict__ degS,
                        float* __restrict__ rs_u, float* __restrict__ rs_i,
                        float* __restrict__ rs_td, float* __restrict__ rs_ts) {
    int i = blockIdx.x * blockDim.x + threadIdx.x;
    if (i < NU) {
        int du = (degU[i] & 0xffff) + (degU[i] >> 16);
        rs_u[i]  = rsqrtf((float)(du < 1 ? 1 : du));
        int dt = (degT[i] & 0xffff) + (degT[i] >> 16);
        rs_td[i] = rsqrtf((float)(dt < 1 ? 1 : dt));
        int ds = degS[i];
        rs_ts[i] = rsqrtf((float)(ds < 1 ? 1 : ds));
    }
    if (i < NI) {
        int d = degI[i];
        int di = (d & 255) + ((d >> 8) & 255) + ((d >> 16) & 255) + ((d >> 24) & 255);
        rs_i[i] = rsqrtf((float)(di < 1 ? 1 : di));
    }
}

// emb fp32 -> packed fp16 cur AND fp16 res (same bits)
__global__ void k_inith(const float* __restrict__ src, uint2* __restrict__ cur,
                        uint2* __restrict__ res, int n4) {
    int i = blockIdx.x * blockDim.x + threadIdx.x;
    if (i >= n4) return;
    float4 v = ((const float4*)src)[i];
    uint2 u;
    u.x = ((unsigned)__half_as_ushort(__float2half(v.y)) << 16) |
           (unsigned)__half_as_ushort(__float2half(v.x));
    u.y = ((unsigned)__half_as_ushort(__float2half(v.w)) << 16) |
           (unsigned)__half_as_ushort(__float2half(v.z));
    cur[i] = u;
    res[i] = u;
}

// ---------- gather: 2 nodes per wave (32-lane groups), 2 cols per lane ----------

__device__ __forceinline__ void gather32(const int* __restrict__ col, int b, int d,
                                         const float* __restrict__ rs,
                                         const __half2* __restrict__ rows, int gl,
                                         float2& acc) {
    int e = b + d;
    for (int k0 = b; k0 < e; k0 += 32) {
        int idx = k0 + gl;
        int   n = idx < e ? col[idx] : 0;
        float r = idx < e ? rs[n] : 0.f;
        #pragma unroll
        for (int j = 0; j < 32; ++j) {
            int   nn = __shfl(n, j, 32);
            float rr = __shfl(r, j, 32);
            float2 f = __half22float2(rows[(size_t)nn * 32 + gl]);
            acc.x += rr * f.x;
            acc.y += rr * f.y;
        }
    }
}

__device__ __forceinline__ void gather8(const int* __restrict__ col, int b, int d,
                                        const float* __restrict__ rs,
                                        const __half2* __restrict__ rows, int gl,
                                        float2& acc) {
    int e = b + d;
    int sub = gl & 7;
    for (int k0 = b; k0 < e; k0 += 8) {
        int idx = k0 + sub;
        int   n = idx < e ? col[idx] : 0;
        float r = idx < e ? rs[n] : 0.f;
        #pragma unroll
        for (int j = 0; j < 8; ++j) {
            int   nn = __shfl(n, j, 32);
            float rr = __shfl(r, j, 32);
            float2 f = __half22float2(rows[(size_t)nn * 32 + gl]);
            acc.x += rr * f.x;
            acc.y += rr * f.y;
        }
    }
}

// user update: class-ordered rate gathers (ci slices), then trust gathers (cu slices)
__global__ void k_user(const int* __restrict__ colU, const int* __restrict__ degU,
                       const int* __restrict__ colT, const int* __restrict__ degT,
                       const float* __restrict__ rs_u, const float* __restrict__ rs_i,
                       const float* __restrict__ rs_ts, const float* __restrict__ rs_td,
                       const __half2* __restrict__ cu, const __half2* __restrict__ ci,
                       __half2* __restrict__ nu, __half2* __restrict__ resu) {
    int wid = threadIdx.x >> 6;
    int lane = threadIdx.x & 63;
    int grp = lane >> 5;
    int gl  = lane & 31;
    int node = (blockIdx.x * 4 + wid) * 2 + grp;
    if (node >= NU) return;
    int d = degU[node];
    int l0 = d & 0xffff, l1 = d >> 16;
    int base = node * CAPU;
    float2 acc = {0.f, 0.f}, acc2 = {0.f, 0.f};
    gather32(colU, base, l0, rs_i, ci, gl, acc);
    gather32(colU, base + CAPU - l1, l1, rs_i, ci, gl, acc);
    int dT = degT[node];
    int t0 = dT & 0xffff, t1 = dT >> 16;
    int baseT = node * CAPT;
    gather8(colT, baseT, t0, rs_ts, cu, gl, acc2);
    gather8(colT, baseT + CAPT - t1, t1, rs_ts, cu, gl, acc2);
    float su = rs_u[node], st = rs_td[node];
    float vx = su * acc.x + st * acc2.x;
    float vy = su * acc.y + st * acc2.y;
    size_t o = (size_t)node * 32 + gl;
    nu[o] = __floats2half2_rn(vx, vy);
    float2 old = __half22float2(resu[o]);
    resu[o] = __floats2half2_rn(old.x + vx, old.y + vy);
}

// item update: 4-class ordered gathers over cu slices
__global__ void k_item(const int* __restrict__ colI, const int* __restrict__ degI,
                       const float* __restrict__ rs_i, const float* __restrict__ rs_u,
                       const __half2* __restrict__ cu,
                       __half2* __restrict__ ni, __half2* __restrict__ resi) {
    int wid = threadIdx.x >> 6;
    int lane = threadIdx.x & 63;
    int grp = lane >> 5;
    int gl  = lane & 31;
    int node = (blockIdx.x * 4 + wid) * 2 + grp;
    if (node >= NI) return;
    int d = degI[node];
    int b0 = d & 255, b1 = (d >> 8) & 255, b2 = (d >> 16) & 255, b3 = (d >> 24) & 255;
    int base = node * CAPI;
    float2 acc = {0.f, 0.f};
    gather32(colI, base,            b0, rs_u, cu, gl, acc);
    gather32(colI, base + 48 - b1,  b1, rs_u, cu, gl, acc);
    gather32(colI, base + 48,       b2, rs_u, cu, gl, acc);
    gather32(colI, base + CAPI - b3, b3, rs_u, cu, gl, acc);
    float si = rs_i[node];
    float vx = si * acc.x, vy = si * acc.y;
    size_t o = (size_t)node * 32 + gl;
    ni[o] = __floats2half2_rn(vx, vy);
    float2 old = __half22float2(resi[o]);
    resi[o] = __floats2half2_rn(old.x + vx, old.y + vy);
}

// ---------------- prediction (fp16 res rows) ----------------

__global__ void k_pred(const int* __restrict__ pu, const int* __restrict__ pi,
                       const int* __restrict__ nuv, const int* __restrict__ niv,
                       const __half2* __restrict__ ru, const __half2* __restrict__ ri,
                       float* __restrict__ out, int E) {
    long long tid = (long long)blockIdx.x * blockDim.x + threadIdx.x;
    int e = (int)(tid >> 4);
    int c2 = ((int)tid & 15) * 2;
    if (e >= 2 * E) return;
    int ee = (e < E) ? e : e - E;
    int u  = (e < E) ? pu[ee] : nuv[ee];
    int it = (e < E) ? pi[ee] : niv[ee];
    float2 a0 = __half22float2(ru[(size_t)u  * 32 + c2]);
    float2 a1 = __half22float2(ru[(size_t)u  * 32 + c2 + 1]);
    float2 b0 = __half22float2(ri[(size_t)it * 32 + c2]);
    float2 b1 = __half22float2(ri[(size_t)it * 32 + c2 + 1]);
    float s = a0.x * b0.x + a0.y * b0.y + a1.x * b1.x + a1.y * b1.y;
    s += __shfl_xor(s, 1); s += __shfl_xor(s, 2);
    s += __shfl_xor(s, 4); s += __shfl_xor(s, 8);
    if (((int)tid & 15) == 0) out[e] = s * (1.0f / 16.0f);  // (1/4)*(1/4) fold
}

extern "C" void kernel_launch(void* const* d_in, const int* in_sizes, int n_in,
                              void* d_out, int out_size, void* d_ws, size_t ws_size,
                              hipStream_t stream) {
    const float* emb_u  = (const float*)d_in[0];
    const float* emb_i  = (const float*)d_in[1];
    const int* rate_u   = (const int*)d_in[2];
    const int* rate_i   = (const int*)d_in[3];
    const int* trust_s  = (const int*)d_in[4];
    const int* trust_d  = (const int*)d_in[5];
    const int* pos_u    = (const int*)d_in[6];
    const int* pos_i    = (const int*)d_in[7];
    const int* neg_u    = (const int*)d_in[8];
    const int* neg_i    = (const int*)d_in[9];
    const int E_rate  = in_sizes[2];
    const int E_trust = in_sizes[4];
    const int E_pred  = in_sizes[6];

    // ---- workspace carve ----
    int* iw   = (int*)d_ws;
    int* degU = iw;                          // NU
    int* degI = degU + NU;                   // NI
    int* degT = degI + NI;                   // NU
    int* degS = degT + NU;                   // NU
    int* bc1  = degS + NU;                   // 256
    int* bc2  = bc1 + NB1;                   // 256
    int* bc3  = bc2 + NB2;                   // 128
    int* bc4  = bc3 + NB3;                   // 128
    int* colU = bc4 + NB4;                   // NU*CAPU
    int* colI = colU + (size_t)NU * CAPU;    // NI*CAPI
    int* colT = colI + (size_t)NI * CAPI;    // NU*CAPT
    float* rs_u  = (float*)(colT + (size_t)NU * CAPT);  // NU
    float* rs_i  = rs_u  + NU;               // NI
    float* rs_ts = rs_i  + NI;               // NU
    float* rs_td = rs_ts + NU;               // NU
    __half2* uA   = (__half2*)(rs_td + NU);  // NU*32
    __half2* uB   = uA + (size_t)NU * 32;    // NU*32
    __half2* iA   = uB + (size_t)NU * 32;    // NI*32
    __half2* iB   = iA + (size_t)NI * 32;    // NI*32
    __half2* res_u = iB + (size_t)NI * 32;   // NU*32
    __half2* res_i = res_u + (size_t)NU * 32; // NI*32
    // bins alias the half2 region (consumed before k_inith runs)
    u64* bins1 = (u64*)uA;
    u64* bins2 = bins1 + (size_t)NB1 * CAPB1;
    u64* bins3 = bins2 + (size_t)NB2 * CAPB2;
    u64* bins4 = bins3 + (size_t)NB3 * CAPB3;

    hipMemsetAsync(bc1, 0, (NB1 + NB2 + NB3 + NB4) * sizeof(int), stream);

    k_binAll<<<GR + GT, 1024, 0, stream>>>(rate_u, rate_i, trust_s, trust_d,
                                           bc1, bc2, bc3, bc4,
                                           bins1, bins2, bins3, bins4,
                                           E_rate, E_trust);
    k_buildAll<<<NB1 + NB2 + NB3 + NB4, 512, 0, stream>>>(
        bins1, bins2, bins3, bins4, bc1, bc2, bc3, bc4,
        colU, colI, colT, degU, degI, degT, degS);

    k_degrs<<<(NU + BS - 1) / BS, BS, 0, stream>>>(degU, degI, degT, degS,
                                                   rs_u, rs_i, rs_td, rs_ts);

    // init AFTER buildAll (uA..res region aliased by bins)
    k_inith<<<(NU * D / 4 + BS - 1) / BS, BS, 0, stream>>>(emb_u, (uint2*)uA, (uint2*)res_u, NU * D / 4);
    k_inith<<<(NI * D / 4 + BS - 1) / BS, BS, 0, stream>>>(emb_i, (uint2*)iA, (uint2*)res_i, NI * D / 4);

    __half2* cu = uA; __half2* nu_ = uB;
    __half2* ci = iA; __half2* ni_ = iB;
    for (int l = 0; l < 3; ++l) {
        k_user<<<12500, BS, 0, stream>>>(colU, degU, colT, degT,
                                         rs_u, rs_i, rs_ts, rs_td,
                                         cu, ci, nu_, res_u);
        k_item<<<6250, BS, 0, stream>>>(colI, degI, rs_i, rs_u,
                                        cu, ni_, res_i);
        __half2* t;
        t = cu; cu = nu_; nu_ = t;
        t = ci; ci = ni_; ni_ = t;
    }

    long long tp = (long long)2 * E_pred * 16;
    k_pred<<<(unsigned)((tp + BS - 1) / BS), BS, 0, stream>>>(
        pos_u, pos_i, neg_u, neg_i, res_u, res_i, (float*)d_out, E_pred);
}

// Round 9
// 366.286 us; speedup vs baseline: 1.6671x; 1.6671x over previous
//
#include <hip/hip_runtime.h>
#include <hip/hip_fp16.h>

#define NU 100000
#define NI 50000
#define D  64
#define CAPU 64   // rate slots per user
#define CAPI 96   // rate slots per item
#define CAPT 32   // trust slots per dst
#define BS 256

// counting-sort geometry
#define NB1 256
#define KPB1 391
#define CAPB1 9216
#define NB2 256
#define KPB2 196
#define CAPB2 9216
#define NB3 128
#define KPB3 782
#define CAPB3 4864
#define NB4 128
#define CAPB4 4864
#define GR 224
#define GT 32

typedef unsigned long long u64;

// ---------------- pass A: LDS-histogram binning, 4 sorts at once ----------------
__global__ void __launch_bounds__(1024) k_binAll(
    const int* __restrict__ ru, const int* __restrict__ ri,
    const int* __restrict__ ts, const int* __restrict__ td,
    int* __restrict__ bc1, int* __restrict__ bc2,
    int* __restrict__ bc3, int* __restrict__ bc4,
    u64* __restrict__ bins1, u64* __restrict__ bins2,
    u64* __restrict__ bins3, u64* __restrict__ bins4,
    int E_rate, int E_trust)
{
    __shared__ int cnt[512];
    __shared__ int base[512];
    int b = blockIdx.x, tid = threadIdx.x;
    if (b < GR) {
        if (tid < 512) cnt[tid] = 0;
        __syncthreads();
        for (int c0 = b * 1024; c0 < E_rate; c0 += GR * 1024) {
            int e = c0 + tid;
            if (e < E_rate) {
                int u = ru[e], it = ri[e];
                atomicAdd(&cnt[u / KPB1], 1);
                atomicAdd(&cnt[256 + it / KPB2], 1);
            }
        }
        __syncthreads();
        if (tid < 256)      base[tid] = atomicAdd(&bc1[tid], cnt[tid]);
        else if (tid < 512) base[tid] = atomicAdd(&bc2[tid - 256], cnt[tid]);
        __syncthreads();
        if (tid < 512) cnt[tid] = 0;
        __syncthreads();
        for (int c0 = b * 1024; c0 < E_rate; c0 += GR * 1024) {
            int e = c0 + tid;
            if (e < E_rate) {
                int u = ru[e], it = ri[e];
                int b1 = u / KPB1, b2 = it / KPB2;
                int r1 = atomicAdd(&cnt[b1], 1);
                int o1 = base[b1] + r1;
                if (o1 < CAPB1) bins1[(size_t)b1 * CAPB1 + o1] = ((u64)u << 32) | (unsigned)it;
                int r2 = atomicAdd(&cnt[256 + b2], 1);
                int o2 = base[256 + b2] + r2;
                if (o2 < CAPB2) bins2[(size_t)b2 * CAPB2 + o2] = ((u64)it << 32) | (unsigned)u;
            }
        }
    } else {
        int bb = b - GR;
        if (tid < 256) cnt[tid] = 0;
        __syncthreads();
        for (int c0 = bb * 1024; c0 < E_trust; c0 += GT * 1024) {
            int e = c0 + tid;
            if (e < E_trust) {
                int s = ts[e], dd = td[e];
                atomicAdd(&cnt[dd / KPB3], 1);
                atomicAdd(&cnt[128 + s / KPB3], 1);
            }
        }
        __syncthreads();
        if (tid < 128)      base[tid] = atomicAdd(&bc3[tid], cnt[tid]);
        else if (tid < 256) base[tid] = atomicAdd(&bc4[tid - 128], cnt[tid]);
        __syncthreads();
        if (tid < 256) cnt[tid] = 0;
        __syncthreads();
        for (int c0 = bb * 1024; c0 < E_trust; c0 += GT * 1024) {
            int e = c0 + tid;
            if (e < E_trust) {
                int s = ts[e], dd = td[e];
                int b3 = dd / KPB3, b4 = s / KPB3;
                int r3 = atomicAdd(&cnt[b3], 1);
                int o3 = base[b3] + r3;
                if (o3 < CAPB3) bins3[(size_t)b3 * CAPB3 + o3] = ((u64)dd << 32) | (unsigned)s;
                int r4 = atomicAdd(&cnt[128 + b4], 1);
                int o4 = base[128 + b4] + r4;
                if (o4 < CAPB4) bins4[(size_t)b4 * CAPB4 + o4] = ((u64)s << 32);
            }
        }
    }
}

// ---------------- pass B: one block per bucket, LDS cursors, plain col stores ----------------
__global__ void __launch_bounds__(512) k_buildAll(
    const u64* __restrict__ bins1, const u64* __restrict__ bins2,
    const u64* __restrict__ bins3, const u64* __restrict__ bins4,
    const int* __restrict__ bc1, const int* __restrict__ bc2,
    const int* __restrict__ bc3, const int* __restrict__ bc4,
    int* __restrict__ colU, int* __restrict__ colI, int* __restrict__ colT,
    int* __restrict__ degU, int* __restrict__ degI,
    int* __restrict__ degT, int* __restrict__ degS)
{
    __shared__ int cnt[KPB3];
    int b = blockIdx.x, tid = threadIdx.x;
    const u64* bins; int n, k0, kpb, colcap, nmax; int* col; int* deg;
    if (b < NB1) {
        bins = bins1 + (size_t)b * CAPB1; n = bc1[b]; if (n > CAPB1) n = CAPB1;
        k0 = b * KPB1; kpb = KPB1; colcap = CAPU; col = colU; deg = degU; nmax = NU;
    } else if (b < NB1 + NB2) {
        int q = b - NB1;
        bins = bins2 + (size_t)q * CAPB2; n = bc2[q]; if (n > CAPB2) n = CAPB2;
        k0 = q * KPB2; kpb = KPB2; colcap = CAPI; col = colI; deg = degI; nmax = NI;
    } else if (b < NB1 + NB2 + NB3) {
        int q = b - NB1 - NB2;
        bins = bins3 + (size_t)q * CAPB3; n = bc3[q]; if (n > CAPB3) n = CAPB3;
        k0 = q * KPB3; kpb = KPB3; colcap = CAPT; col = colT; deg = degT; nmax = NU;
    } else {
        int q = b - NB1 - NB2 - NB3;
        bins = bins4 + (size_t)q * CAPB4; n = bc4[q]; if (n > CAPB4) n = CAPB4;
        k0 = q * KPB3; kpb = KPB3; colcap = 0; col = nullptr; deg = degS; nmax = NU;
    }
    for (int t = tid; t < kpb; t += 512) cnt[t] = 0;
    __syncthreads();
    if (col) {
        for (int i = tid; i < n; i += 512) {
            u64 e = bins[i];
            int k = (int)(e >> 32);
            int v = (int)(e & 0xffffffffu);
            int c = atomicAdd(&cnt[k - k0], 1);
            if (c < colcap) col[(size_t)k * colcap + c] = v;
        }
    } else {
        for (int i = tid; i < n; i += 512) {
            int k = (int)(bins[i] >> 32);
            atomicAdd(&cnt[k - k0], 1);
        }
    }
    __syncthreads();
    for (int t = tid; t < kpb; t += 512) {
        int k = k0 + t;
        if (k < nmax) {
            int c = cnt[t];
            if (colcap && c > colcap) c = colcap;
            deg[k] = c;
        }
    }
}

// rs arrays; rs_tsu = rs_ts / rs_u (trust source weight applied on pre-scaled cuR)
__global__ void k_degrs(const int* __restrict__ degU, const int* __restrict__ degI,
                        const int* __restrict__ degT, const int* __restrict__ degS,
                        float* __restrict__ rs_u, float* __restrict__ rs_i,
                        float* __restrict__ rs_td, float* __restrict__ rs_tsu) {
    int i = blockIdx.x * blockDim.x + threadIdx.x;
    if (i < NU) {
        int a = degU[i]; float ru = rsqrtf((float)(a < 1 ? 1 : a));
        rs_u[i] = ru;
        int b = degT[i]; rs_td[i] = rsqrtf((float)(b < 1 ? 1 : b));
        int c = degS[i]; rs_tsu[i] = rsqrtf((float)(c < 1 ? 1 : c)) / ru;
    }
    if (i < NI) {
        int a = degI[i]; rs_i[i] = rsqrtf((float)(a < 1 ? 1 : a));
    }
}

__device__ __forceinline__ uint2 pack4(float a, float b, float c, float d) {
    __half2 lo = __floats2half2_rn(a, b);
    __half2 hi = __floats2half2_rn(c, d);
    uint2 r;
    r.x = *(unsigned*)&lo;
    r.y = *(unsigned*)&hi;
    return r;
}

// emb fp32 -> curS = rs*emb (fp16), res = emb (fp16). i indexes uint2 (4 floats).
__global__ void k_inith(const float* __restrict__ src, const float* __restrict__ rs,
                        uint2* __restrict__ curS, uint2* __restrict__ res, int n16) {
    int i = blockIdx.x * blockDim.x + threadIdx.x;
    if (i >= n16) return;
    float4 v = ((const float4*)src)[i];
    float s = rs[i >> 4];
    res[i]  = pack4(v.x, v.y, v.z, v.w);
    curS[i] = pack4(s * v.x, s * v.y, s * v.z, s * v.w);
}

// zero-rows (row NU of user tables, row NI of item tables) for padded gather lanes
__global__ void k_zrow(uint2* uA, uint2* uB, uint2* iA, uint2* iB) {
    int t = threadIdx.x;
    int e = t & 15;
    uint2 z; z.x = 0; z.y = 0;
    if (t < 16)      uA[(size_t)NU * 16 + e] = z;
    else if (t < 32) uB[(size_t)NU * 16 + e] = z;
    else if (t < 48) iA[(size_t)NI * 16 + e] = z;
    else             iB[(size_t)NI * 16 + e] = z;
}

// ---------------- fused layer: 16-lane groups, 4 nodes/wave, uint2 rows ----------------
// user blocks : item blocks = 2 : 1 (m = blockIdx%3)
__global__ void k_layer(const int* __restrict__ colU, const int* __restrict__ degU,
                        const int* __restrict__ colT, const int* __restrict__ degT,
                        const int* __restrict__ colI, const int* __restrict__ degI,
                        const float* __restrict__ rs_u, const float* __restrict__ rs_i,
                        const float* __restrict__ rs_td, const float* __restrict__ rs_tsu,
                        const uint2* __restrict__ cuR, const uint2* __restrict__ ciS,
                        uint2* __restrict__ nuR, uint2* __restrict__ niS,
                        uint2* __restrict__ resu, uint2* __restrict__ resi) {
    int b = blockIdx.x;
    int m = b % 3;
    int base = b / 3;
    int wid = threadIdx.x >> 6;
    int lane = threadIdx.x & 63;
    int grp = lane >> 4;
    int gl  = lane & 15;
    if (m < 2) {
        int node = ((base * 2 + m) * 4 + wid) * 4 + grp;
        if (node >= NU) return;
        float4 acc = {0.f, 0.f, 0.f, 0.f};
        {   // weightless rate gather from pre-scaled ciS; zrow = NI
            int bb = node * CAPU, e = bb + degU[node];
            for (int k0 = bb; k0 < e; k0 += 16) {
                int idx = k0 + gl;
                int n = idx < e ? colU[idx] : NI;
                #pragma unroll
                for (int j = 0; j < 16; ++j) {
                    int nn = __shfl(n, j, 16);
                    uint2 q = ciS[(size_t)nn * 16 + gl];
                    float2 f = __half22float2(*(__half2*)&q.x);
                    float2 g = __half22float2(*(__half2*)&q.y);
                    acc.x += f.x; acc.y += f.y; acc.z += g.x; acc.w += g.y;
                }
            }
        }
        float4 acc2 = {0.f, 0.f, 0.f, 0.f};
        {   // weighted trust gather from cuR with w = rs_tsu
            int bb = node * CAPT, e = bb + degT[node];
            int sub = gl & 7;
            for (int k0 = bb; k0 < e; k0 += 8) {
                int idx = k0 + sub;
                int n = idx < e ? colT[idx] : NU;
                float w = idx < e ? rs_tsu[n] : 0.f;
                #pragma unroll
                for (int j = 0; j < 8; ++j) {
                    int nn  = __shfl(n, j, 16);
                    float ww = __shfl(w, j, 16);
                    uint2 q = cuR[(size_t)nn * 16 + gl];
                    float2 f = __half22float2(*(__half2*)&q.x);
                    float2 g = __half22float2(*(__half2*)&q.y);
                    acc2.x += ww * f.x; acc2.y += ww * f.y;
                    acc2.z += ww * g.x; acc2.w += ww * g.y;
                }
            }
        }
        float su = rs_u[node], st = rs_td[node];
        float vx = su * acc.x + st * acc2.x;
        float vy = su * acc.y + st * acc2.y;
        float vz = su * acc.z + st * acc2.z;
        float vw = su * acc.w + st * acc2.w;
        size_t o = (size_t)node * 16 + gl;
        nuR[o] = pack4(su * vx, su * vy, su * vz, su * vw);  // pre-scaled for next layer
        uint2 r = resu[o];
        float2 ra = __half22float2(*(__half2*)&r.x);
        float2 rb = __half22float2(*(__half2*)&r.y);
        resu[o] = pack4(ra.x + vx, ra.y + vy, rb.x + vz, rb.y + vw);
    } else {
        int node = (base * 4 + wid) * 4 + grp;
        if (node >= NI) return;
        float4 acc = {0.f, 0.f, 0.f, 0.f};
        {   // weightless rate gather from pre-scaled cuR; zrow = NU
            int bb = node * CAPI, e = bb + degI[node];
            for (int k0 = bb; k0 < e; k0 += 16) {
                int idx = k0 + gl;
                int n = idx < e ? colI[idx] : NU;
                #pragma unroll
                for (int j = 0; j < 16; ++j) {
                    int nn = __shfl(n, j, 16);
                    uint2 q = cuR[(size_t)nn * 16 + gl];
                    float2 f = __half22float2(*(__half2*)&q.x);
                    float2 g = __half22float2(*(__half2*)&q.y);
                    acc.x += f.x; acc.y += f.y; acc.z += g.x; acc.w += g.y;
                }
            }
        }
        float si = rs_i[node];
        float vx = si * acc.x, vy = si * acc.y, vz = si * acc.z, vw = si * acc.w;
        size_t o = (size_t)node * 16 + gl;
        niS[o] = pack4(si * vx, si * vy, si * vz, si * vw);
        uint2 r = resi[o];
        float2 ra = __half22float2(*(__half2*)&r.x);
        float2 rb = __half22float2(*(__half2*)&r.y);
        resi[o] = pack4(ra.x + vx, ra.y + vy, rb.x + vz, rb.y + vw);
    }
}

// ---------------- prediction (fp16 res rows) ----------------
__global__ void k_pred(const int* __restrict__ pu, const int* __restrict__ pi,
                       const int* __restrict__ nuv, const int* __restrict__ niv,
                       const __half2* __restrict__ ru, const __half2* __restrict__ ri,
                       float* __restrict__ out, int E) {
    long long tid = (long long)blockIdx.x * blockDim.x + threadIdx.x;
    int e = (int)(tid >> 4);
    int c2 = ((int)tid & 15) * 2;
    if (e >= 2 * E) return;
    int ee = (e < E) ? e : e - E;
    int u  = (e < E) ? pu[ee] : nuv[ee];
    int it = (e < E) ? pi[ee] : niv[ee];
    float2 a0 = __half22float2(ru[(size_t)u  * 32 + c2]);
    float2 a1 = __half22float2(ru[(size_t)u  * 32 + c2 + 1]);
    float2 b0 = __half22float2(ri[(size_t)it * 32 + c2]);
    float2 b1 = __half22float2(ri[(size_t)it * 32 + c2 + 1]);
    float s = a0.x * b0.x + a0.y * b0.y + a1.x * b1.x + a1.y * b1.y;
    s += __shfl_xor(s, 1); s += __shfl_xor(s, 2);
    s += __shfl_xor(s, 4); s += __shfl_xor(s, 8);
    if (((int)tid & 15) == 0) out[e] = s * (1.0f / 16.0f);  // (1/4)*(1/4) fold
}

extern "C" void kernel_launch(void* const* d_in, const int* in_sizes, int n_in,
                              void* d_out, int out_size, void* d_ws, size_t ws_size,
                              hipStream_t stream) {
    const float* emb_u  = (const float*)d_in[0];
    const float* emb_i  = (const float*)d_in[1];
    const int* rate_u   = (const int*)d_in[2];
    const int* rate_i   = (const int*)d_in[3];
    const int* trust_s  = (const int*)d_in[4];
    const int* trust_d  = (const int*)d_in[5];
    const int* pos_u    = (const int*)d_in[6];
    const int* pos_i    = (const int*)d_in[7];
    const int* neg_u    = (const int*)d_in[8];
    const int* neg_i    = (const int*)d_in[9];
    const int E_rate  = in_sizes[2];
    const int E_trust = in_sizes[4];
    const int E_pred  = in_sizes[6];

    // ---- workspace carve ----
    int* iw   = (int*)d_ws;
    int* degU = iw;                          // NU
    int* degI = degU + NU;                   // NI
    int* degT = degI + NI;                   // NU
    int* degS = degT + NU;                   // NU
    int* bc1  = degS + NU;                   // 256
    int* bc2  = bc1 + NB1;                   // 256
    int* bc3  = bc2 + NB2;                   // 128
    int* bc4  = bc3 + NB3;                   // 128
    int* colU = bc4 + NB4;                   // NU*CAPU
    int* colI = colU + (size_t)NU * CAPU;    // NI*CAPI
    int* colT = colI + (size_t)NI * CAPI;    // NU*CAPT
    float* rs_u   = (float*)(colT + (size_t)NU * CAPT);  // NU
    float* rs_i   = rs_u  + NU;              // NI
    float* rs_td  = rs_i  + NI;              // NU
    float* rs_tsu = rs_td + NU;              // NU
    uint2* uRA  = (uint2*)(rs_tsu + NU);     // (NU+1)*16 (zrow at NU)
    uint2* uRB  = uRA + (size_t)(NU + 1) * 16;
    uint2* iSA  = uRB + (size_t)(NU + 1) * 16;   // (NI+1)*16
    uint2* iSB  = iSA + (size_t)(NI + 1) * 16;
    uint2* res_u = iSB + (size_t)(NI + 1) * 16;  // NU*16
    uint2* res_i = res_u + (size_t)NU * 16;      // NI*16
    // bins alias the half2 region (consumed before k_inith/k_zrow run)
    u64* bins1 = (u64*)uRA;
    u64* bins2 = bins1 + (size_t)NB1 * CAPB1;
    u64* bins3 = bins2 + (size_t)NB2 * CAPB2;
    u64* bins4 = bins3 + (size_t)NB3 * CAPB3;

    hipMemsetAsync(bc1, 0, (NB1 + NB2 + NB3 + NB4) * sizeof(int), stream);

    k_binAll<<<GR + GT, 1024, 0, stream>>>(rate_u, rate_i, trust_s, trust_d,
                                           bc1, bc2, bc3, bc4,
                                           bins1, bins2, bins3, bins4,
                                           E_rate, E_trust);
    k_buildAll<<<NB1 + NB2 + NB3 + NB4, 512, 0, stream>>>(
        bins1, bins2, bins3, bins4, bc1, bc2, bc3, bc4,
        colU, colI, colT, degU, degI, degT, degS);

    k_degrs<<<(NU + BS - 1) / BS, BS, 0, stream>>>(degU, degI, degT, degS,
                                                   rs_u, rs_i, rs_td, rs_tsu);

    // init AFTER buildAll (region aliased by bins)
    k_inith<<<(NU * 16 + BS - 1) / BS, BS, 0, stream>>>(emb_u, rs_u, uRA, res_u, NU * 16);
    k_inith<<<(NI * 16 + BS - 1) / BS, BS, 0, stream>>>(emb_i, rs_i, iSA, res_i, NI * 16);
    k_zrow<<<1, 64, 0, stream>>>(uRA, uRB, iSA, iSB);

    uint2* cu = uRA; uint2* nu_ = uRB;
    uint2* ci = iSA; uint2* ni_ = iSB;
    for (int l = 0; l < 3; ++l) {
        k_layer<<<9375, BS, 0, stream>>>(colU, degU, colT, degT, colI, degI,
                                         rs_u, rs_i, rs_td, rs_tsu,
                                         cu, ci, nu_, ni_, res_u, res_i);
        uint2* t;
        t = cu; cu = nu_; nu_ = t;
        t = ci; ci = ni_; ni_ = t;
    }

    long long tp = (long long)2 * E_pred * 16;
    k_pred<<<(unsigned)((tp + BS - 1) / BS), BS, 0, stream>>>(
        pos_u, pos_i, neg_u, neg_i, (const __half2*)res_u, (const __half2*)res_i,
        (float*)d_out, E_pred);
}